// Round 5
// baseline (343.162 us; speedup 1.0000x reference)
//
#include <hip/hip_runtime.h>
#include <math.h>

// Heat equation, temporally blocked, K=16 steps/launch, 16 dispatches total.
// Block: 64x64 core + 16 halo -> 96x96 tile in LDS, row stride padded to 100
// floats (96 % 32 == 0 caused multi-way bank conflicts on every ds_read).
// Double buffered (76.8 KB), 1024 threads. Loop-invariant addresses, store
// predicates and boundary masks hoisted out of the 16-step loop. Frame 0 is
// written during the first dispatch's tile load (no separate init kernel).
// Barriers drain lgkmcnt only; global frame stores stay in flight.

#define CORE 64
#define HALO 16
#define REG  96            // CORE + 2*HALO (logical tile)
#define PAD  100           // padded LDS row stride in floats
#define TPB  1024
#define NIT  (94 * 24)     // 2256 interior quads per step

__device__ __forceinline__ void slot_init(int it, int o_r, int o_c, int nX,
                                          int& a, size_t& so, bool& st, float4& m) {
    const int r = 1 + it / 24;
    const int q = it % 24;
    a = r * PAD + 4 * q;
    const int gr  = o_r + r;
    const int gc0 = o_c + 4 * q;
    so = (size_t)gr * nX + gc0;
    st = (r >= HALO && r < HALO + CORE && q >= HALO / 4 && q < (REG - HALO) / 4);
    const bool rin = (gr > 0 && gr < nX - 1);
    m.x = (rin && gc0     > 0 && gc0     < nX - 1) ? 1.f : 0.f;
    m.y = (rin && gc0 + 1 > 0 && gc0 + 1 < nX - 1) ? 1.f : 0.f;
    m.z = (rin && gc0 + 2 > 0 && gc0 + 2 < nX - 1) ? 1.f : 0.f;
    m.w = (rin && gc0 + 3 > 0 && gc0 + 3 < nX - 1) ? 1.f : 0.f;
}

__device__ __forceinline__ void step_one(const float* __restrict__ bc,
                                         float* __restrict__ bn,
                                         float* __restrict__ of,
                                         int a, size_t so, bool st,
                                         const float4& m, float4& c, float gamma) {
    const float4 u4 = *reinterpret_cast<const float4*>(bc + a - PAD);
    const float4 d4 = *reinterpret_cast<const float4*>(bc + a + PAD);
    const float lf = bc[a - 1];
    const float rt = bc[a + 4];
    float4 o;
    o.x = m.x * (c.x + gamma * (u4.x + d4.x + lf  + c.y - 4.f * c.x));
    o.y = m.y * (c.y + gamma * (u4.y + d4.y + c.x + c.z - 4.f * c.y));
    o.z = m.z * (c.z + gamma * (u4.z + d4.z + c.y + c.w - 4.f * c.z));
    o.w = m.w * (c.w + gamma * (u4.w + d4.w + c.z + rt  - 4.f * c.w));
    *reinterpret_cast<float4*>(bn + a) = o;
    if (st) *reinterpret_cast<float4*>(of + so) = o;
    c = o;   // this step's output is next step's center
}

__global__ __launch_bounds__(TPB)
void heat_fused(const float* __restrict__ src,       // u0 (first) or frame t_base
                float* __restrict__ out,             // full output base
                int t_base, int k, int nX, int first,
                int time_steps,
                const float* __restrict__ alpha_p,
                const int* __restrict__ T_p) {
    __shared__ float buf[2][REG * PAD];

    const int tid = threadIdx.x;
    const int gb  = nX / CORE;                 // 16
    const int bx  = blockIdx.x % gb;
    const int by  = blockIdx.x / gb;
    const int o_r = by * CORE - HALO;
    const int o_c = bx * CORE - HALO;

    const float alpha = *alpha_p;
    const float Tf    = (float)(*T_p);
    const float dx    = 6.0f / (float)(nX - 1);
    const float dt    = Tf / (float)(time_steps - 1);
    const float gamma = alpha * dt / (dx * dx);

    // ---- load 96x96 tile (strict interior mask: boundaries/OOD -> 0).
    // Frames always have zero boundaries, and for first==1 this mask also
    // produces reference frame 0 from u0 — which we store inline.
    for (int idx = tid; idx < REG * PAD; idx += TPB) {
        const int r = idx / PAD, c = idx % PAD;
        const int gr = o_r + r, gc = o_c + c;
        float v = 0.f;
        if (c < REG && gr > 0 && gr < nX - 1 && gc > 0 && gc < nX - 1)
            v = src[(size_t)gr * nX + gc];
        buf[0][idx] = v;
        if (first && r >= HALO && r < HALO + CORE && c >= HALO && c < HALO + CORE)
            out[(size_t)gr * nX + gc] = v;           // frame 0
    }
    asm volatile("s_waitcnt lgkmcnt(0)" ::: "memory");
    __builtin_amdgcn_s_barrier();
    __builtin_amdgcn_sched_barrier(0);

    // ---- per-slot loop invariants ----
    int a0, a1, a2 = PAD; size_t so0, so1, so2 = 0; bool st0, st1, st2 = false;
    float4 m0, m1, m2;
    slot_init(tid,           o_r, o_c, nX, a0, so0, st0, m0);
    slot_init(tid + TPB,     o_r, o_c, nX, a1, so1, st1, m1);
    const bool has2 = (tid + 2 * TPB) < NIT;
    if (has2) slot_init(tid + 2 * TPB, o_r, o_c, nX, a2, so2, st2, m2);

    float4 c0 = *reinterpret_cast<const float4*>(&buf[0][a0]);
    float4 c1 = *reinterpret_cast<const float4*>(&buf[0][a1]);
    float4 c2 = make_float4(0.f, 0.f, 0.f, 0.f);
    if (has2) c2 = *reinterpret_cast<const float4*>(&buf[0][a2]);

    int cur = 0;
    for (int s = 0; s < k; ++s) {
        const float* __restrict__ bc = buf[cur];
        float*       __restrict__ bn = buf[cur ^ 1];
        float* of = out + (size_t)(t_base + s + 1) * nX * nX;

        step_one(bc, bn, of, a0, so0, st0, m0, c0, gamma);
        step_one(bc, bn, of, a1, so1, st1, m1, c1, gamma);
        if (has2) step_one(bc, bn, of, a2, so2, st2, m2, c2, gamma);

        // LDS-only drain; global stores remain in flight across the barrier
        asm volatile("s_waitcnt lgkmcnt(0)" ::: "memory");
        __builtin_amdgcn_s_barrier();
        __builtin_amdgcn_sched_barrier(0);
        cur ^= 1;
    }
}

extern "C" void kernel_launch(void* const* d_in, const int* in_sizes, int n_in,
                              void* d_out, int out_size, void* d_ws, size_t ws_size,
                              hipStream_t stream) {
    const float* u0      = (const float*)d_in[0];
    const float* alpha_p = (const float*)d_in[1];
    const int*   T_p     = (const int*)d_in[2];

    const int n0 = in_sizes[0];                   // nX*nX
    const int nX = (int)(sqrtf((float)n0) + 0.5f);
    const int ts = out_size / n0;                 // time_steps

    float* out = (float*)d_out;
    const int gb = nX / CORE;                     // 16
    const int nblocks = gb * gb;                  // 256

    for (int t = 0; t < ts - 1; t += HALO) {
        const int k = min(HALO, ts - 1 - t);
        const float* src = (t == 0) ? u0 : out + (size_t)t * n0;
        heat_fused<<<nblocks, TPB, 0, stream>>>(src, out, t, k, nX,
                                                (t == 0) ? 1 : 0, ts,
                                                alpha_p, T_p);
    }
}